// Round 8
// baseline (3530.686 us; speedup 1.0000x reference)
//
#include <hip/hip_runtime.h>
#include <cstdint>
#include <cstddef>

#define A_N 100000
#define B_N 200000
#define M_N 20000
#define HD 256
#define MAX_NB 10
#define N_MOLS 2000
#define ATOM_FDIM 35
#define FB_DIM 40

#define BM 64

typedef unsigned short u16;

// Static device buffers. Messages stored bf16: pool = 2*102.4 + 10.2 MB.
__device__ u16 g_msg0[(size_t)B_N * HD];
__device__ u16 g_msg1[(size_t)B_N * HD];
__device__ u16 g_tmsgh[(size_t)M_N * HD];
__device__ float g_counts[N_MOLS];

__device__ __forceinline__ u16 f2b(float f)
{
    union { float f; unsigned u; } x; x.f = f;
    const unsigned r = x.u + 0x7FFFu + ((x.u >> 16) & 1u);
    return (u16)(r >> 16);
}
__device__ __forceinline__ float blo(unsigned u) { return __uint_as_float(u << 16); }
__device__ __forceinline__ float bhi(unsigned u) { return __uint_as_float(u & 0xffff0000u); }

// ---------------- zero fill / convert ----------------
__global__ __launch_bounds__(256)
void k_zero_out(float* __restrict__ p, int n)
{
    const int i = blockIdx.x * 256 + threadIdx.x;
    if (i < n) p[i] = 0.f;
}

__global__ __launch_bounds__(256)
void k_zero_counts()
{
    const int i = blockIdx.x * 256 + threadIdx.x;
    if (i < N_MOLS) g_counts[i] = 0.f;
}

__global__ __launch_bounds__(256)
void k_cvt(const float* __restrict__ tmsg)
{
    const int i = (blockIdx.x * 256 + threadIdx.x) * 4;
    if (i < M_N * HD) {
        const float4 v = *(const float4*)(tmsg + i);
        ushort4 o;
        o.x = f2b(v.x); o.y = f2b(v.y); o.z = f2b(v.z); o.w = f2b(v.w);
        *(ushort4*)(g_tmsgh + i) = o;
    }
}

// ---------------- K1: g_msg0 = bf16(relu(fbonds @ W_i)) ----------------
__global__ __launch_bounds__(256)
void k_in(const float* __restrict__ fbonds, const float* __restrict__ Wi)
{
    __shared__ float Ws[FB_DIM * HD];                      // 40 KB
    for (int i = threadIdx.x; i < FB_DIM * HD; i += 256) Ws[i] = Wi[i];
    __syncthreads();
    const int lane = threadIdx.x & 63;
    const int wid  = (blockIdx.x * 256 + threadIdx.x) >> 6;
    const int nw   = (gridDim.x * 256) >> 6;
    for (int row = wid; row < B_N; row += nw) {
        const float* fr = fbonds + (size_t)row * FB_DIM;
        float ax = 0.f, ay = 0.f, az = 0.f, aw = 0.f;
        #pragma unroll
        for (int q = 0; q < FB_DIM / 4; ++q) {
            const float4 fv = *(const float4*)(fr + q * 4);
            const float fa[4] = {fv.x, fv.y, fv.z, fv.w};
            #pragma unroll
            for (int t = 0; t < 4; ++t) {
                const float4 w = *(const float4*)&Ws[(q * 4 + t) * HD + lane * 4];
                ax += fa[t] * w.x; ay += fa[t] * w.y;
                az += fa[t] * w.z; aw += fa[t] * w.w;
            }
        }
        ushort4 o;
        o.x = f2b(fmaxf(ax, 0.f)); o.y = f2b(fmaxf(ay, 0.f));
        o.z = f2b(fmaxf(az, 0.f)); o.w = f2b(fmaxf(aw, 0.f));
        *(ushort4*)(g_msg0 + (size_t)row * HD + lane * 4) = o;
    }
}

// ------- K2 (x2): dst = bf16(relu(fbonds@W_i + gather(bgraph,[tmsg;src]) @ W_h)) -------
// R7 post-mortem: acc[4][16]=64 regs + 20 outstanding gather uint4s (80 regs)
// still overflowed the 128-reg budget -> acc scratch round-trips (~1.5 GB).
// This version: 512 threads, acc[2][16]=32 regs, gather = ONE uint4 per nb
// (8 lanes x 16 B = one row's 64-wide K slice). Peak demand ~100 regs: no spill.
__global__ __launch_bounds__(512, 2)
void k_mp(const int* __restrict__ bgraph, const float* __restrict__ Wh,
          const float* __restrict__ fbonds, const float* __restrict__ Wi,
          int srcSel)
{
    const u16* gsrc = srcSel ? g_msg1 : g_msg0;
    u16* gdst       = srcSel ? g_msg0 : g_msg1;

    __shared__ float As[64][68];                // 17.4 KB  [k][row], 64-wide K slice
    __shared__ float Bs[32][260];               // 33.3 KB  32-row half-slice of Wh
    __shared__ const u16* ptr_s[BM][MAX_NB];    // 5 KB
    float (*wi_s)[132] = (float(*)[132])Bs;     // 40x132 = 21.1 KB overlay (epilogue)
    float (*fb_s)[44]  = (float(*)[44])As;      // 64x44  = 11.3 KB overlay (epilogue)

    const int tid = threadIdx.x;
    const int rowBase = blockIdx.x * BM;

    for (int idx = tid; idx < BM * MAX_NB; idx += 512) {
        const int r = idx / MAX_NB;
        const int j = idx - r * MAX_NB;
        const int id = bgraph[(size_t)(rowBase + r) * MAX_NB + j];
        ptr_s[r][j] = (id < M_N) ? (g_tmsgh + (size_t)id * HD)
                                 : (gsrc + (size_t)(id - M_N) * HD);
    }
    __syncthreads();

    const int r   = tid >> 3;              // [0,64) gather row
    const int kq8 = (tid & 7) << 3;        // {0,8,...,56}: 8 lanes cover 64-wide K
    const int tx = tid & 15;               // col group
    const int ty = tid >> 4;               // [0,32): 2 rows per thread
    float acc[2][16] = {};

    #pragma unroll 1
    for (int k0 = 0; k0 < HD; k0 += 64) {
        // gather-sum: one uint4 (8 bf16) per neighbor
        float s[8] = {0.f,0.f,0.f,0.f,0.f,0.f,0.f,0.f};
        #pragma unroll
        for (int j = 0; j < MAX_NB; ++j) {
            const uint4 v = *(const uint4*)(ptr_s[r][j] + k0 + kq8);
            s[0] += blo(v.x); s[1] += bhi(v.x);
            s[2] += blo(v.y); s[3] += bhi(v.y);
            s[4] += blo(v.z); s[5] += bhi(v.z);
            s[6] += blo(v.w); s[7] += bhi(v.w);
        }
        #pragma unroll
        for (int t = 0; t < 8; ++t) As[kq8 + t][r] = s[t];

        // two 32-row Wh half-slices
        #pragma unroll 1
        for (int h2 = 0; h2 < 2; ++h2) {
            #pragma unroll
            for (int i = 0; i < 4; ++i) {
                const int idx = tid + i * 512;
                const int kk = idx >> 6;
                const int c4 = (idx & 63) << 2;
                *(float4*)&Bs[kk][c4] =
                    *(const float4*)(Wh + (size_t)(k0 + 32 * h2 + kk) * HD + c4);
            }
            __syncthreads();
            #pragma unroll 4
            for (int kk = 0; kk < 32; ++kk) {
                const float2 a = *(const float2*)&As[32 * h2 + kk][ty * 2];
                #pragma unroll
                for (int g = 0; g < 4; ++g) {
                    const float4 b = *(const float4*)&Bs[kk][g * 64 + tx * 4];
                    acc[0][g*4+0] += a.x * b.x; acc[0][g*4+1] += a.x * b.y;
                    acc[0][g*4+2] += a.x * b.z; acc[0][g*4+3] += a.x * b.w;
                    acc[1][g*4+0] += a.y * b.x; acc[1][g*4+1] += a.y * b.y;
                    acc[1][g*4+2] += a.y * b.z; acc[1][g*4+3] += a.y * b.w;
                }
            }
            __syncthreads();
        }
    }

    // ---- epilogue, fully static ----
    for (int idx = tid; idx < BM * 10; idx += 512) {
        const int rr = idx / 10;
        const int q = idx - rr * 10;
        *(float4*)&fb_s[rr][q * 4] =
            *(const float4*)(fbonds + (size_t)(rowBase + rr) * FB_DIM + q * 4);
    }
    for (int idx = tid; idx < 1280; idx += 512) {
        const int k = idx >> 5;
        const int c4 = (idx & 31) << 2;
        *(float4*)&wi_s[k][c4] = *(const float4*)(Wi + (size_t)k * HD + c4);
    }
    __syncthreads();

    // h = 0 : cols [0,128)
    #pragma unroll
    for (int i = 0; i < 2; ++i) {
        const int lr = ty * 2 + i;
        float a0 = acc[i][0], a1 = acc[i][1], a2 = acc[i][2], a3 = acc[i][3];
        float a4 = acc[i][4], a5 = acc[i][5], a6 = acc[i][6], a7 = acc[i][7];
        #pragma unroll
        for (int k = 0; k < FB_DIM; ++k) {
            const float f = fb_s[lr][k];
            const float4 b0 = *(const float4*)&wi_s[k][tx * 4];
            const float4 b1 = *(const float4*)&wi_s[k][64 + tx * 4];
            a0 += f * b0.x; a1 += f * b0.y; a2 += f * b0.z; a3 += f * b0.w;
            a4 += f * b1.x; a5 += f * b1.y; a6 += f * b1.z; a7 += f * b1.w;
        }
        const size_t base = (size_t)(rowBase + lr) * HD;
        ushort4 o0, o1;
        o0.x = f2b(fmaxf(a0, 0.f)); o0.y = f2b(fmaxf(a1, 0.f));
        o0.z = f2b(fmaxf(a2, 0.f)); o0.w = f2b(fmaxf(a3, 0.f));
        o1.x = f2b(fmaxf(a4, 0.f)); o1.y = f2b(fmaxf(a5, 0.f));
        o1.z = f2b(fmaxf(a6, 0.f)); o1.w = f2b(fmaxf(a7, 0.f));
        *(ushort4*)(gdst + base + tx * 4) = o0;
        *(ushort4*)(gdst + base + 64 + tx * 4) = o1;
    }
    __syncthreads();
    for (int idx = tid; idx < 1280; idx += 512) {
        const int k = idx >> 5;
        const int c4 = (idx & 31) << 2;
        *(float4*)&wi_s[k][c4] = *(const float4*)(Wi + (size_t)k * HD + 128 + c4);
    }
    __syncthreads();
    // h = 1 : cols [128,256)
    #pragma unroll
    for (int i = 0; i < 2; ++i) {
        const int lr = ty * 2 + i;
        float a0 = acc[i][8],  a1 = acc[i][9],  a2 = acc[i][10], a3 = acc[i][11];
        float a4 = acc[i][12], a5 = acc[i][13], a6 = acc[i][14], a7 = acc[i][15];
        #pragma unroll
        for (int k = 0; k < FB_DIM; ++k) {
            const float f = fb_s[lr][k];
            const float4 b0 = *(const float4*)&wi_s[k][tx * 4];
            const float4 b1 = *(const float4*)&wi_s[k][64 + tx * 4];
            a0 += f * b0.x; a1 += f * b0.y; a2 += f * b0.z; a3 += f * b0.w;
            a4 += f * b1.x; a5 += f * b1.y; a6 += f * b1.z; a7 += f * b1.w;
        }
        const size_t base = (size_t)(rowBase + lr) * HD + 128;
        ushort4 o0, o1;
        o0.x = f2b(fmaxf(a0, 0.f)); o0.y = f2b(fmaxf(a1, 0.f));
        o0.z = f2b(fmaxf(a2, 0.f)); o0.w = f2b(fmaxf(a3, 0.f));
        o1.x = f2b(fmaxf(a4, 0.f)); o1.y = f2b(fmaxf(a5, 0.f));
        o1.z = f2b(fmaxf(a6, 0.f)); o1.w = f2b(fmaxf(a7, 0.f));
        *(ushort4*)(gdst + base + tx * 4) = o0;
        *(ushort4*)(gdst + base + 64 + tx * 4) = o1;
    }
}

// ------- K3: out += segsum(relu([fatoms|gather(agraph,msg)] @ W_o + b)) -------
// (unchanged from R7 — not the dominant dispatch; revisit after k_mp lands)
__global__ __launch_bounds__(256, 3)
void k_final(const int* __restrict__ agraph, const float* __restrict__ fatoms,
             const float* __restrict__ Wo, const float* __restrict__ bias,
             const int* __restrict__ scope, float* __restrict__ outsum)
{
    const u16* gm = g_msg0;
    __shared__ float As[32][68];
    __shared__ float Bs[32][260];
    __shared__ const u16* ptr_s[BM][MAX_NB];
    const int tid = threadIdx.x;
    const int rowBase = blockIdx.x * BM;

    for (int idx = tid; idx < BM * MAX_NB; idx += 256) {
        const int rr = idx / MAX_NB;
        const int j = idx - rr * MAX_NB;
        const int ra = rowBase + rr;
        const int id = (ra < A_N) ? agraph[(size_t)ra * MAX_NB + j] : 0;  // tmsg row0 = 0
        ptr_s[rr][j] = (id < M_N) ? (g_tmsgh + (size_t)id * HD)
                                  : (gm + (size_t)(id - M_N) * HD);
    }
    __syncthreads();

    const int r   = tid >> 2;
    const int kq8 = (tid & 3) << 3;
    const int ra  = rowBase + r;
    const bool va = ra < A_N;
    const int tx = tid & 15;
    const int ty = tid >> 4;
    float acc[4][16] = {};

    #pragma unroll 1
    for (int k0 = 0; k0 < 320; k0 += 32) {
        const int k = k0 + kq8;
        if (k >= 40 && k < 296) {
            const int off = k - 40;
            float s[8] = {0.f,0.f,0.f,0.f,0.f,0.f,0.f,0.f};
            #pragma unroll
            for (int j = 0; j < MAX_NB; ++j) {
                const uint4 v = *(const uint4*)(ptr_s[r][j] + off);
                s[0] += blo(v.x); s[1] += bhi(v.x);
                s[2] += blo(v.y); s[3] += bhi(v.y);
                s[4] += blo(v.z); s[5] += bhi(v.z);
                s[6] += blo(v.w); s[7] += bhi(v.w);
            }
            #pragma unroll
            for (int t = 0; t < 8; ++t) As[kq8 + t][r] = s[t];
        } else {
            #pragma unroll
            for (int t = 0; t < 8; ++t) {
                const int kk2 = k + t;
                float x = 0.f;
                if (kk2 < ATOM_FDIM && va) x = fatoms[(size_t)ra * ATOM_FDIM + kk2];
                As[kq8 + t][r] = x;
            }
        }
        #pragma unroll
        for (int i = 0; i < 8; ++i) {
            const int idx = tid + i * 256;
            const int kk = idx >> 6;
            const int c4 = (idx & 63) << 2;
            const int kg = k0 + kk;
            float4 v = {0.f, 0.f, 0.f, 0.f};
            if (kg < ATOM_FDIM)
                v = *(const float4*)(Wo + (size_t)kg * HD + c4);
            else if (kg >= 40 && kg < 296)
                v = *(const float4*)(Wo + (size_t)(kg - 5) * HD + c4);
            *(float4*)&Bs[kk][c4] = v;
        }
        __syncthreads();
        #pragma unroll 4
        for (int kk = 0; kk < 32; ++kk) {
            const float4 a = *(const float4*)&As[kk][ty * 4];
            const float av[4] = {a.x, a.y, a.z, a.w};
            #pragma unroll
            for (int g = 0; g < 4; ++g) {
                const float4 b = *(const float4*)&Bs[kk][g * 64 + tx * 4];
                const float bv[4] = {b.x, b.y, b.z, b.w};
                #pragma unroll
                for (int i = 0; i < 4; ++i)
                    #pragma unroll
                    for (int q = 0; q < 4; ++q)
                        acc[i][g * 4 + q] += av[i] * bv[q];
            }
        }
        __syncthreads();
    }

    float bb[16];
    #pragma unroll
    for (int g = 0; g < 4; ++g) {
        const float4 b = *(const float4*)(bias + g * 64 + tx * 4);
        bb[g*4+0] = b.x; bb[g*4+1] = b.y; bb[g*4+2] = b.z; bb[g*4+3] = b.w;
    }
    float s[16] = {};
    int prev = -1;
    #pragma unroll
    for (int i = 0; i < 4; ++i) {
        const int rr = rowBase + ty * 4 + i;
        if (rr < A_N) {
            const int m = scope[rr];
            if (m != prev) {
                if (prev >= 0) {
                    float* dst = outsum + (size_t)prev * HD;
                    #pragma unroll
                    for (int g = 0; g < 4; ++g)
                        #pragma unroll
                        for (int q = 0; q < 4; ++q)
                            atomicAdd(dst + g * 64 + tx * 4 + q, s[g * 4 + q]);
                    #pragma unroll
                    for (int q = 0; q < 16; ++q) s[q] = 0.f;
                }
                prev = m;
            }
            #pragma unroll
            for (int q = 0; q < 16; ++q)
                s[q] += fmaxf(acc[i][q] + bb[q], 0.f);
        }
    }
    if (prev >= 0) {
        float* dst = outsum + (size_t)prev * HD;
        #pragma unroll
        for (int g = 0; g < 4; ++g)
            #pragma unroll
            for (int q = 0; q < 4; ++q)
                atomicAdd(dst + g * 64 + tx * 4 + q, s[g * 4 + q]);
    }
}

// ---------------- counts + divide ----------------
__global__ __launch_bounds__(256)
void k_counts(const int* __restrict__ scope)
{
    const int a = blockIdx.x * 256 + threadIdx.x;
    if (a < A_N) atomicAdd(&g_counts[scope[a]], 1.0f);
}

__global__ __launch_bounds__(256)
void k_div(float* __restrict__ out)
{
    const int idx = blockIdx.x * 256 + threadIdx.x;
    out[idx] = out[idx] / fmaxf(g_counts[idx >> 8], 1.0f);
}

// ---------------- launch ----------------
extern "C" void kernel_launch(void* const* d_in, const int* in_sizes, int n_in,
                              void* d_out, int out_size, void* d_ws, size_t ws_size,
                              hipStream_t stream)
{
    const float* fatoms = (const float*)d_in[0];
    const float* fbonds = (const float*)d_in[1];
    const int*   agraph = (const int*)d_in[2];
    const int*   bgraph = (const int*)d_in[3];
    const float* tmsg   = (const float*)d_in[4];
    const int*   scope  = (const int*)d_in[5];
    const float* W_i    = (const float*)d_in[6];
    const float* W_h    = (const float*)d_in[7];
    const float* W_o    = (const float*)d_in[8];
    const float* W_ob   = (const float*)d_in[9];
    float* out = (float*)d_out;

    (void)d_ws; (void)ws_size;

    k_zero_out<<<(N_MOLS * HD + 255) / 256, 256, 0, stream>>>(out, N_MOLS * HD);
    k_zero_counts<<<(N_MOLS + 255) / 256, 256, 0, stream>>>();
    k_cvt<<<(M_N * HD / 4 + 255) / 256, 256, 0, stream>>>(tmsg);

    k_in<<<4096, 256, 0, stream>>>(fbonds, W_i);
    k_mp<<<B_N / BM, 512, 0, stream>>>(bgraph, W_h, fbonds, W_i, 0);
    k_mp<<<B_N / BM, 512, 0, stream>>>(bgraph, W_h, fbonds, W_i, 1);
    k_counts<<<(A_N + 255) / 256, 256, 0, stream>>>(scope);
    k_final<<<(A_N + BM - 1) / BM, 256, 0, stream>>>(agraph, fatoms, W_o, W_ob, scope, out);
    k_div<<<(N_MOLS * HD) / 256, 256, 0, stream>>>(out);
}

// Round 9
// 1921.936 us; speedup vs baseline: 1.8370x; 1.8370x over previous
//
#include <hip/hip_runtime.h>
#include <cstdint>
#include <cstddef>

#define A_N 100000
#define B_N 200000
#define M_N 20000
#define POOL_N 220000   // M_N + B_N
#define HD 256
#define MAX_NB 10
#define N_MOLS 2000
#define ATOM_FDIM 35
#define FB_DIM 40

#define BM 64

typedef unsigned short u16;

// Static device buffers (BSS, ~532 MB).
__device__ u16 g_msg0[(size_t)B_N * HD];         // 102.4 MB bf16 messages
__device__ u16 g_msg1[(size_t)B_N * HD];         // 102.4 MB
__device__ u16 g_tmsgh[(size_t)M_N * HD];        // 10.2 MB bf16 tree messages
__device__ u16 g_P[(size_t)POOL_N * HD];         // 112.6 MB  P = pool @ W_h (bf16)
__device__ float g_binput[(size_t)B_N * HD];     // 204.8 MB fp32 binput (loop-invariant)
__device__ float g_counts[N_MOLS];

__device__ __forceinline__ u16 f2b(float f)
{
    union { float f; unsigned u; } x; x.f = f;
    const unsigned r = x.u + 0x7FFFu + ((x.u >> 16) & 1u);
    return (u16)(r >> 16);
}
__device__ __forceinline__ unsigned pack2(float a, float b)
{
    return (unsigned)f2b(a) | ((unsigned)f2b(b) << 16);
}
__device__ __forceinline__ float blo(unsigned u) { return __uint_as_float(u << 16); }
__device__ __forceinline__ float bhi(unsigned u) { return __uint_as_float(u & 0xffff0000u); }

// ---------------- zero fill / convert ----------------
__global__ __launch_bounds__(256)
void k_zero_out(float* __restrict__ p, int n)
{
    const int i = blockIdx.x * 256 + threadIdx.x;
    if (i < n) p[i] = 0.f;
}

__global__ __launch_bounds__(256)
void k_zero_counts()
{
    const int i = blockIdx.x * 256 + threadIdx.x;
    if (i < N_MOLS) g_counts[i] = 0.f;
}

__global__ __launch_bounds__(256)
void k_cvt(const float* __restrict__ tmsg)
{
    const int i = (blockIdx.x * 256 + threadIdx.x) * 4;
    if (i < M_N * HD) {
        const float4 v = *(const float4*)(tmsg + i);
        ushort4 o;
        o.x = f2b(v.x); o.y = f2b(v.y); o.z = f2b(v.z); o.w = f2b(v.w);
        *(ushort4*)(g_tmsgh + i) = o;
    }
}

// ------- K1: binput = fbonds @ W_i (fp32, stored); g_msg0 = bf16(relu(binput)) -------
__global__ __launch_bounds__(256)
void k_in(const float* __restrict__ fbonds, const float* __restrict__ Wi)
{
    __shared__ float Ws[FB_DIM * HD];                      // 40 KB
    for (int i = threadIdx.x; i < FB_DIM * HD; i += 256) Ws[i] = Wi[i];
    __syncthreads();
    const int lane = threadIdx.x & 63;
    const int wid  = (blockIdx.x * 256 + threadIdx.x) >> 6;
    const int nw   = (gridDim.x * 256) >> 6;
    for (int row = wid; row < B_N; row += nw) {
        const float* fr = fbonds + (size_t)row * FB_DIM;
        float ax = 0.f, ay = 0.f, az = 0.f, aw = 0.f;
        #pragma unroll
        for (int q = 0; q < FB_DIM / 4; ++q) {
            const float4 fv = *(const float4*)(fr + q * 4);
            const float fa[4] = {fv.x, fv.y, fv.z, fv.w};
            #pragma unroll
            for (int t = 0; t < 4; ++t) {
                const float4 w = *(const float4*)&Ws[(q * 4 + t) * HD + lane * 4];
                ax += fa[t] * w.x; ay += fa[t] * w.y;
                az += fa[t] * w.z; aw += fa[t] * w.w;
            }
        }
        const size_t base = (size_t)row * HD + lane * 4;
        float4 bi; bi.x = ax; bi.y = ay; bi.z = az; bi.w = aw;
        *(float4*)(g_binput + base) = bi;
        ushort4 o;
        o.x = f2b(fmaxf(ax, 0.f)); o.y = f2b(fmaxf(ay, 0.f));
        o.z = f2b(fmaxf(az, 0.f)); o.w = f2b(fmaxf(aw, 0.f));
        *(ushort4*)(g_msg0 + base) = o;
    }
}

// ------- K2: P[rowStart:rowEnd] = bf16( pool_row @ W_h ) — DENSE GEMM, no gather -------
// Linearity: (sum_j msg[idx_j]) @ Wh == sum_j (msg[idx_j] @ Wh), so transform the
// pool once, then the per-bond update is a pure gather of P (k_gather below).
// acc[2][16]=32 regs, unroll 2 -> peak demand ~85 regs, well under the 128 cap.
__global__ __launch_bounds__(512, 2)
void k_gemmP(const float* __restrict__ Wh, int srcSel, int rowStart, int rowEnd)
{
    const u16* msrc = srcSel ? g_msg1 : g_msg0;

    __shared__ float As[64][68];                // 17.4 KB  [k][row]
    __shared__ float Bs[32][260];               // 33.3 KB  32-row half-slice of Wh

    const int tid = threadIdx.x;
    const int rowBase = rowStart + blockIdx.x * BM;

    // A-stage addressing: one uint4 (8 bf16) per thread per k0
    const int r   = tid >> 3;              // [0,64)
    const int kq8 = (tid & 7) << 3;        // {0,8,...,56}
    int arow = rowBase + r;
    if (arow >= rowEnd) arow = rowEnd - 1; // clamp (reads only; stores guarded)
    const u16* aptr = (arow < M_N) ? (g_tmsgh + (size_t)arow * HD)
                                   : (msrc + (size_t)(arow - M_N) * HD);

    const int tx = tid & 15;
    const int ty = tid >> 4;               // [0,32)
    float acc[2][16] = {};

    #pragma unroll 1
    for (int k0 = 0; k0 < HD; k0 += 64) {
        const uint4 v = *(const uint4*)(aptr + k0 + kq8);
        As[kq8 + 0][r] = blo(v.x); As[kq8 + 1][r] = bhi(v.x);
        As[kq8 + 2][r] = blo(v.y); As[kq8 + 3][r] = bhi(v.y);
        As[kq8 + 4][r] = blo(v.z); As[kq8 + 5][r] = bhi(v.z);
        As[kq8 + 6][r] = blo(v.w); As[kq8 + 7][r] = bhi(v.w);

        #pragma unroll 1
        for (int h2 = 0; h2 < 2; ++h2) {
            #pragma unroll
            for (int i = 0; i < 4; ++i) {
                const int idx = tid + i * 512;
                const int kk = idx >> 6;
                const int c4 = (idx & 63) << 2;
                *(float4*)&Bs[kk][c4] =
                    *(const float4*)(Wh + (size_t)(k0 + 32 * h2 + kk) * HD + c4);
            }
            __syncthreads();
            #pragma unroll 2
            for (int kk = 0; kk < 32; ++kk) {
                const float2 a = *(const float2*)&As[32 * h2 + kk][ty * 2];
                #pragma unroll
                for (int g = 0; g < 4; ++g) {
                    const float4 b = *(const float4*)&Bs[kk][g * 64 + tx * 4];
                    acc[0][g*4+0] += a.x * b.x; acc[0][g*4+1] += a.x * b.y;
                    acc[0][g*4+2] += a.x * b.z; acc[0][g*4+3] += a.x * b.w;
                    acc[1][g*4+0] += a.y * b.x; acc[1][g*4+1] += a.y * b.y;
                    acc[1][g*4+2] += a.y * b.z; acc[1][g*4+3] += a.y * b.w;
                }
            }
            __syncthreads();
        }
    }

    // store P (bf16), fully static
    #pragma unroll
    for (int i = 0; i < 2; ++i) {
        const int row = rowBase + ty * 2 + i;
        if (row < rowEnd) {
            const size_t base = (size_t)row * HD;
            #pragma unroll
            for (int g = 0; g < 4; ++g) {
                ushort4 o;
                o.x = f2b(acc[i][g*4+0]); o.y = f2b(acc[i][g*4+1]);
                o.z = f2b(acc[i][g*4+2]); o.w = f2b(acc[i][g*4+3]);
                *(ushort4*)(g_P + base + g * 64 + tx * 4) = o;
            }
        }
    }
}

// ------- K3: dst = bf16(relu(binput + sum_j P[bgraph[r][j]])) — pure gather -------
// 8 rows/block, 32 threads/row (16 B each). 10 independent uint4 loads/thread,
// zero barriers after index staging: built to run at max outstanding-load depth.
__global__ __launch_bounds__(256)
void k_gather(const int* __restrict__ bgraph, int dstSel)
{
    u16* dst = dstSel ? g_msg1 : g_msg0;
    __shared__ int idx_s[8][MAX_NB];
    const int tid = threadIdx.x;
    const int rowBase = blockIdx.x * 8;
    if (tid < 8 * MAX_NB) {
        const int r = tid / MAX_NB;
        const int j = tid - r * MAX_NB;
        idx_s[r][j] = bgraph[(size_t)(rowBase + r) * MAX_NB + j];
    }
    __syncthreads();
    const int rl = tid >> 5;           // [0,8)
    const int c  = (tid & 31) << 3;    // elem offset, 8 bf16 = 16 B per thread
    const int row = rowBase + rl;

    float s[8] = {0.f,0.f,0.f,0.f,0.f,0.f,0.f,0.f};
    #pragma unroll
    for (int j = 0; j < MAX_NB; ++j) {
        const uint4 v = *(const uint4*)(g_P + (size_t)idx_s[rl][j] * HD + c);
        s[0] += blo(v.x); s[1] += bhi(v.x);
        s[2] += blo(v.y); s[3] += bhi(v.y);
        s[4] += blo(v.z); s[5] += bhi(v.z);
        s[6] += blo(v.w); s[7] += bhi(v.w);
    }
    const float* bp = g_binput + (size_t)row * HD + c;
    const float4 b0 = *(const float4*)(bp);
    const float4 b1 = *(const float4*)(bp + 4);
    uint4 w;
    w.x = pack2(fmaxf(s[0] + b0.x, 0.f), fmaxf(s[1] + b0.y, 0.f));
    w.y = pack2(fmaxf(s[2] + b0.z, 0.f), fmaxf(s[3] + b0.w, 0.f));
    w.z = pack2(fmaxf(s[4] + b1.x, 0.f), fmaxf(s[5] + b1.y, 0.f));
    w.w = pack2(fmaxf(s[6] + b1.z, 0.f), fmaxf(s[7] + b1.w, 0.f));
    *(uint4*)(dst + (size_t)row * HD + c) = w;
}

// ------- K4: out += segsum(relu([fatoms|gather(agraph,msg)] @ W_o + b)) -------
// (unchanged from R7/R8 — raw-message gather, fp32 W_o GEMM, run-aggregated atomics)
__global__ __launch_bounds__(256, 3)
void k_final(const int* __restrict__ agraph, const float* __restrict__ fatoms,
             const float* __restrict__ Wo, const float* __restrict__ bias,
             const int* __restrict__ scope, float* __restrict__ outsum)
{
    const u16* gm = g_msg0;
    __shared__ float As[32][68];
    __shared__ float Bs[32][260];
    __shared__ const u16* ptr_s[BM][MAX_NB];
    const int tid = threadIdx.x;
    const int rowBase = blockIdx.x * BM;

    for (int idx = tid; idx < BM * MAX_NB; idx += 256) {
        const int rr = idx / MAX_NB;
        const int j = idx - rr * MAX_NB;
        const int ra = rowBase + rr;
        const int id = (ra < A_N) ? agraph[(size_t)ra * MAX_NB + j] : 0;  // tmsg row0 = 0
        ptr_s[rr][j] = (id < M_N) ? (g_tmsgh + (size_t)id * HD)
                                  : (gm + (size_t)(id - M_N) * HD);
    }
    __syncthreads();

    const int r   = tid >> 2;
    const int kq8 = (tid & 3) << 3;
    const int ra  = rowBase + r;
    const bool va = ra < A_N;
    const int tx = tid & 15;
    const int ty = tid >> 4;
    float acc[4][16] = {};

    #pragma unroll 1
    for (int k0 = 0; k0 < 320; k0 += 32) {
        const int k = k0 + kq8;
        if (k >= 40 && k < 296) {
            const int off = k - 40;
            float s[8] = {0.f,0.f,0.f,0.f,0.f,0.f,0.f,0.f};
            #pragma unroll
            for (int j = 0; j < MAX_NB; ++j) {
                const uint4 v = *(const uint4*)(ptr_s[r][j] + off);
                s[0] += blo(v.x); s[1] += bhi(v.x);
                s[2] += blo(v.y); s[3] += bhi(v.y);
                s[4] += blo(v.z); s[5] += bhi(v.z);
                s[6] += blo(v.w); s[7] += bhi(v.w);
            }
            #pragma unroll
            for (int t = 0; t < 8; ++t) As[kq8 + t][r] = s[t];
        } else {
            #pragma unroll
            for (int t = 0; t < 8; ++t) {
                const int kk2 = k + t;
                float x = 0.f;
                if (kk2 < ATOM_FDIM && va) x = fatoms[(size_t)ra * ATOM_FDIM + kk2];
                As[kq8 + t][r] = x;
            }
        }
        #pragma unroll
        for (int i = 0; i < 8; ++i) {
            const int idx = tid + i * 256;
            const int kk = idx >> 6;
            const int c4 = (idx & 63) << 2;
            const int kg = k0 + kk;
            float4 v = {0.f, 0.f, 0.f, 0.f};
            if (kg < ATOM_FDIM)
                v = *(const float4*)(Wo + (size_t)kg * HD + c4);
            else if (kg >= 40 && kg < 296)
                v = *(const float4*)(Wo + (size_t)(kg - 5) * HD + c4);
            *(float4*)&Bs[kk][c4] = v;
        }
        __syncthreads();
        #pragma unroll 4
        for (int kk = 0; kk < 32; ++kk) {
            const float4 a = *(const float4*)&As[kk][ty * 4];
            const float av[4] = {a.x, a.y, a.z, a.w};
            #pragma unroll
            for (int g = 0; g < 4; ++g) {
                const float4 b = *(const float4*)&Bs[kk][g * 64 + tx * 4];
                const float bv[4] = {b.x, b.y, b.z, b.w};
                #pragma unroll
                for (int i = 0; i < 4; ++i)
                    #pragma unroll
                    for (int q = 0; q < 4; ++q)
                        acc[i][g * 4 + q] += av[i] * bv[q];
            }
        }
        __syncthreads();
    }

    float bb[16];
    #pragma unroll
    for (int g = 0; g < 4; ++g) {
        const float4 b = *(const float4*)(bias + g * 64 + tx * 4);
        bb[g*4+0] = b.x; bb[g*4+1] = b.y; bb[g*4+2] = b.z; bb[g*4+3] = b.w;
    }
    float s[16] = {};
    int prev = -1;
    #pragma unroll
    for (int i = 0; i < 4; ++i) {
        const int rr = rowBase + ty * 4 + i;
        if (rr < A_N) {
            const int m = scope[rr];
            if (m != prev) {
                if (prev >= 0) {
                    float* dstp = outsum + (size_t)prev * HD;
                    #pragma unroll
                    for (int g = 0; g < 4; ++g)
                        #pragma unroll
                        for (int q = 0; q < 4; ++q)
                            atomicAdd(dstp + g * 64 + tx * 4 + q, s[g * 4 + q]);
                    #pragma unroll
                    for (int q = 0; q < 16; ++q) s[q] = 0.f;
                }
                prev = m;
            }
            #pragma unroll
            for (int q = 0; q < 16; ++q)
                s[q] += fmaxf(acc[i][q] + bb[q], 0.f);
        }
    }
    if (prev >= 0) {
        float* dstp = outsum + (size_t)prev * HD;
        #pragma unroll
        for (int g = 0; g < 4; ++g)
            #pragma unroll
            for (int q = 0; q < 4; ++q)
                atomicAdd(dstp + g * 64 + tx * 4 + q, s[g * 4 + q]);
    }
}

// ---------------- counts + divide ----------------
__global__ __launch_bounds__(256)
void k_counts(const int* __restrict__ scope)
{
    const int a = blockIdx.x * 256 + threadIdx.x;
    if (a < A_N) atomicAdd(&g_counts[scope[a]], 1.0f);
}

__global__ __launch_bounds__(256)
void k_div(float* __restrict__ out)
{
    const int idx = blockIdx.x * 256 + threadIdx.x;
    out[idx] = out[idx] / fmaxf(g_counts[idx >> 8], 1.0f);
}

// ---------------- launch ----------------
extern "C" void kernel_launch(void* const* d_in, const int* in_sizes, int n_in,
                              void* d_out, int out_size, void* d_ws, size_t ws_size,
                              hipStream_t stream)
{
    const float* fatoms = (const float*)d_in[0];
    const float* fbonds = (const float*)d_in[1];
    const int*   agraph = (const int*)d_in[2];
    const int*   bgraph = (const int*)d_in[3];
    const float* tmsg   = (const float*)d_in[4];
    const int*   scope  = (const int*)d_in[5];
    const float* W_i    = (const float*)d_in[6];
    const float* W_h    = (const float*)d_in[7];
    const float* W_o    = (const float*)d_in[8];
    const float* W_ob   = (const float*)d_in[9];
    float* out = (float*)d_out;

    (void)d_ws; (void)ws_size;

    k_zero_out<<<(N_MOLS * HD + 255) / 256, 256, 0, stream>>>(out, N_MOLS * HD);
    k_zero_counts<<<(N_MOLS + 255) / 256, 256, 0, stream>>>();
    k_cvt<<<(M_N * HD / 4 + 255) / 256, 256, 0, stream>>>(tmsg);

    k_in<<<4096, 256, 0, stream>>>(fbonds, W_i);            // binput + msg0

    // iter 0: P = [tmsg; msg0] @ Wh (full pool), then msg1 = relu(binput + gatherP)
    k_gemmP<<<(POOL_N + BM - 1) / BM, 512, 0, stream>>>(W_h, 0, 0, POOL_N);
    k_gather<<<B_N / 8, 256, 0, stream>>>(bgraph, 1);

    // iter 1: only msg rows of P change (tmsg part invariant)
    k_gemmP<<<B_N / BM, 512, 0, stream>>>(W_h, 1, M_N, POOL_N);
    k_gather<<<B_N / 8, 256, 0, stream>>>(bgraph, 0);

    k_counts<<<(A_N + 255) / 256, 256, 0, stream>>>(scope);
    k_final<<<(A_N + BM - 1) / BM, 256, 0, stream>>>(agraph, fatoms, W_o, W_ob, scope, out);
    k_div<<<(N_MOLS * HD) / 256, 256, 0, stream>>>(out);
}